// Round 1
// baseline (56.477 us; speedup 1.0000x reference)
//
#include <hip/hip_runtime.h>

#define N_TOKS 1024
#define N_ATOMS 4096
#define CS 384
#define CZ 128
#define CATOM 128
#define CPAIR 16
#define NQ 32
#define NK 128
#define NBLK 128          // N_ATOMS / NQ
#define KOFF (-48)        // NQ/2 - NK/2
#define KSEG 32
#define LN_EPS 1e-5f

// ---------------- tok[] : atom -> token via cumsum + searchsorted(right) ----------------
__global__ __launch_bounds__(1024) void k_tok(const int* __restrict__ na, int* __restrict__ tok) {
    __shared__ int ends[N_TOKS];
    int t = threadIdx.x;
    ends[t] = na[t];
    __syncthreads();
    // Hillis-Steele inclusive scan
    for (int off = 1; off < N_TOKS; off <<= 1) {
        int v = (t >= off) ? ends[t - off] : 0;
        __syncthreads();
        ends[t] += v;
        __syncthreads();
    }
    #pragma unroll
    for (int i = 0; i < N_ATOMS / N_TOKS; i++) {
        int a = t + i * N_TOKS;
        int lo = 0, hi = N_TOKS - 1;
        while (lo < hi) {
            int mid = (lo + hi) >> 1;
            if (ends[mid] > a) hi = mid; else lo = mid + 1;
        }
        tok[a] = lo;   // clamped to N_TOKS-1 like JAX OOB gather
    }
}

// ---------------- s = (LN(si)*ln_s_w) @ W_s + b_s, * mask  (4 tokens / block) ----------------
__global__ __launch_bounds__(256) void k_s(const float* __restrict__ si, const float* __restrict__ lnw,
                                           const float* __restrict__ Ws, const float* __restrict__ bs,
                                           const float* __restrict__ mask, float* __restrict__ s_out) {
    __shared__ float xh[4][CS];
    int t = threadIdx.x;
    int tokbase = blockIdx.x * 4;
    int w = t >> 6, l = t & 63;
    {
        const float* row = si + (size_t)(tokbase + w) * CS;
        float v[6]; float sum = 0.f, sq = 0.f;
        #pragma unroll
        for (int i = 0; i < 6; i++) { float x = row[l + 64 * i]; v[i] = x; sum += x; sq += x * x; }
        #pragma unroll
        for (int off = 32; off >= 1; off >>= 1) { sum += __shfl_xor(sum, off); sq += __shfl_xor(sq, off); }
        float mu = sum * (1.f / CS);
        float var = sq * (1.f / CS) - mu * mu;
        float rstd = rsqrtf(var + LN_EPS);
        #pragma unroll
        for (int i = 0; i < 6; i++) { int c = l + 64 * i; xh[w][c] = (v[i] - mu) * rstd * lnw[c]; }
    }
    __syncthreads();
    int d = t & 127, jj = t >> 7;   // jj in {0,1}; tokens jj and jj+2
    float a0 = 0.f, a1 = 0.f;
    for (int c = 0; c < CS; c++) {
        float wv = Ws[(size_t)c * CATOM + d];
        a0 += xh[jj][c] * wv;
        a1 += xh[jj + 2][c] * wv;
    }
    float bd = bs[d];
    int tk0 = tokbase + jj;
    s_out[(size_t)tk0 * CATOM + d] = (a0 + bd) * mask[tk0];
    int tk1 = tokbase + jj + 2;
    s_out[(size_t)tk1 * CATOM + d] = (a1 + bd) * mask[tk1];
}

// ---------------- z at gathered token pairs + plm_out, per (blk, kseg) ----------------
__global__ __launch_bounds__(256) void k_z(const float* __restrict__ zij, const float* __restrict__ lnzw,
                                           const float* __restrict__ Wz, const float* __restrict__ bz,
                                           const int* __restrict__ tok, const float* __restrict__ plm,
                                           float* __restrict__ plm_out) {
    __shared__ float ztile[NQ * KSEG * CPAIR];   // 64 KB
    __shared__ int tokq[NQ], tokk[KSEG];
    __shared__ int qmap[NQ], kmap[KSEG];
    __shared__ int uqtok[NQ], uktok[KSEG];
    __shared__ float kvalid[KSEG];
    __shared__ int s_uq, s_uk;

    int t = threadIdx.x;
    int blk = blockIdx.x, kseg = blockIdx.y;

    if (t < NQ) {
        tokq[t] = tok[blk * NQ + t];
    } else if (t < NQ + KSEG) {
        int kk = t - NQ;
        int kg = blk * NQ + KOFF + kseg * KSEG + kk;
        kvalid[kk] = (kg >= 0 && kg < N_ATOMS) ? 1.0f : 0.0f;
        int kc = min(max(kg, 0), N_ATOMS - 1);
        tokk[kk] = tok[kc];
    }
    __syncthreads();
    if (t == 0) {
        int u = 0;
        for (int q = 0; q < NQ; q++) { if (q == 0 || tokq[q] != tokq[q - 1]) uqtok[u++] = tokq[q]; qmap[q] = u - 1; }
        s_uq = u;
    } else if (t == 64) {
        int u = 0;
        for (int k = 0; k < KSEG; k++) { if (k == 0 || tokk[k] != tokk[k - 1]) uktok[u++] = tokk[k]; kmap[k] = u - 1; }
        s_uk = u;
    }
    __syncthreads();
    int uq = s_uq, uk = s_uk;
    int npairs = uq * uk;   // <= 1024, actual ~72

    for (int p = t; p < npairs; p += 256) {
        int qi = p / uk, ki = p - qi * uk;
        int tq = uqtok[qi], tk = uktok[ki];
        const float* row = zij + ((size_t)tq * N_TOKS + tk) * CZ;
        float sum = 0.f, sq = 0.f;
        for (int c4 = 0; c4 < CZ / 4; c4++) {
            float4 v = *(const float4*)(row + c4 * 4);
            sum += v.x + v.y + v.z + v.w;
            sq  += v.x * v.x + v.y * v.y + v.z * v.z + v.w * v.w;
        }
        float mu = sum * (1.f / CZ);
        float var = sq * (1.f / CZ) - mu * mu;
        float rstd = rsqrtf(var + LN_EPS);
        float acc[CPAIR];
        #pragma unroll
        for (int d = 0; d < CPAIR; d++) acc[d] = bz[d];
        for (int c4 = 0; c4 < CZ / 4; c4++) {
            float4 v = *(const float4*)(row + c4 * 4);
            float xs[4] = {v.x, v.y, v.z, v.w};
            #pragma unroll
            for (int j = 0; j < 4; j++) {
                int c = c4 * 4 + j;
                float x = (xs[j] - mu) * rstd * lnzw[c];
                const float* wrow = Wz + c * CPAIR;
                #pragma unroll
                for (int d = 0; d < CPAIR; d++) acc[d] += x * wrow[d];
            }
        }
        float* zt = &ztile[(qi * KSEG + ki) * CPAIR];
        #pragma unroll
        for (int d = 0; d < CPAIR; d++) zt[d] = acc[d];
    }
    __syncthreads();

    // streaming phase: 32q * 32k * 16d floats = 4096 float4
    const float4* plm4 = (const float4*)plm;
    float4* out4 = (float4*)plm_out;
    #pragma unroll
    for (int i = 0; i < 16; i++) {
        int f = t + i * 256;          // 0..4095
        int d4 = f & 3;
        int kk = (f >> 2) & 31;
        int q  = f >> 7;
        size_t g = (((size_t)(blk * NQ + q) * NK) + (size_t)kseg * KSEG + kk) * (CPAIR / 4) + d4;
        float4 v = plm4[g];
        float vd = kvalid[kk];
        const float4 z = *(const float4*)&ztile[(qmap[q] * KSEG + kmap[kk]) * CPAIR + d4 * 4];
        v.x += vd * z.x; v.y += vd * z.y; v.z += vd * z.z; v.w += vd * z.w;
        out4[g] = v;
    }
}

// ---------------- cl_out = cl + s[tok];  ql = cl_out + rl@W_r + b_r ----------------
__global__ __launch_bounds__(256) void k_cq(const float* __restrict__ cl, const float* __restrict__ rl,
                                            const float* __restrict__ Wr, const float* __restrict__ br,
                                            const float* __restrict__ s, const int* __restrict__ tok,
                                            float* __restrict__ cl_out, float* __restrict__ ql) {
    int t = blockIdx.x * 256 + threadIdx.x;   // over N_ATOMS * 32 float4s
    int a = t >> 5, d4 = t & 31;
    int tk = tok[a];
    float4 c  = ((const float4*)cl)[t];
    float4 sv = ((const float4*)s)[(size_t)tk * 32 + d4];
    float4 co; co.x = c.x + sv.x; co.y = c.y + sv.y; co.z = c.z + sv.z; co.w = c.w + sv.w;
    float x = rl[a * 3 + 0], y = rl[a * 3 + 1], z = rl[a * 3 + 2];
    float4 w0 = ((const float4*)Wr)[d4];
    float4 w1 = ((const float4*)Wr)[32 + d4];
    float4 w2 = ((const float4*)Wr)[64 + d4];
    float4 bb = ((const float4*)br)[d4];
    float4 q;
    q.x = co.x + x * w0.x + y * w1.x + z * w2.x + bb.x;
    q.y = co.y + x * w0.y + y * w1.y + z * w2.y + bb.y;
    q.z = co.z + x * w0.z + y * w1.z + z * w2.z + bb.z;
    q.w = co.w + x * w0.w + y * w1.w + z * w2.w + bb.w;
    ((float4*)cl_out)[t] = co;
    ((float4*)ql)[t] = q;
}

extern "C" void kernel_launch(void* const* d_in, const int* in_sizes, int n_in,
                              void* d_out, int out_size, void* d_ws, size_t ws_size,
                              hipStream_t stream) {
    (void)in_sizes; (void)n_in; (void)out_size; (void)ws_size;
    const float* token_mask = (const float*)d_in[0];
    const int*   num_atoms  = (const int*)d_in[1];
    const float* cl   = (const float*)d_in[2];
    const float* plm  = (const float*)d_in[3];
    const float* si   = (const float*)d_in[4];
    const float* zij  = (const float*)d_in[5];
    const float* rl   = (const float*)d_in[6];
    const float* ln_s_w = (const float*)d_in[7];
    const float* W_s  = (const float*)d_in[8];
    const float* b_s  = (const float*)d_in[9];
    const float* ln_z_w = (const float*)d_in[10];
    const float* W_z  = (const float*)d_in[11];
    const float* b_z  = (const float*)d_in[12];
    const float* W_r  = (const float*)d_in[13];
    const float* b_r  = (const float*)d_in[14];

    float* out_cl  = (float*)d_out;
    float* out_plm = out_cl + (size_t)N_ATOMS * CATOM;
    float* out_ql  = out_plm + (size_t)NBLK * NQ * NK * CPAIR;

    int*   tok_ws = (int*)d_ws;
    float* s_ws   = (float*)((char*)d_ws + N_ATOMS * sizeof(int));

    k_tok<<<1, 1024, 0, stream>>>(num_atoms, tok_ws);
    k_s<<<N_TOKS / 4, 256, 0, stream>>>(si, ln_s_w, W_s, b_s, token_mask, s_ws);
    k_z<<<dim3(NBLK, NK / KSEG), 256, 0, stream>>>(zij, ln_z_w, W_z, b_z, tok_ws, plm, out_plm);
    k_cq<<<(N_ATOMS * 32) / 256, 256, 0, stream>>>(cl, rl, W_r, b_r, s_ws, tok_ws, out_cl, out_ql);
}